// Round 1
// baseline (183.904 us; speedup 1.0000x reference)
//
#include <hip/hip_runtime.h>

// SpatialCorrelationSampler: out[b,(dy+4)*9+(dx+4),y,x] =
//   sum_c f0[b,c,y,x]*f1[b,c,y+dy,x+dx], dy,dx in [-4,4], OOB=0.
// B=4 C=256 H=96 W=160 -> out (4,81,96,160) fp32.
//
// R5: R4 (86.8us rocprof) was LDS-bound with two fixable losses:
//  (a) 7.74M bank-conflict cycles (12.6us): stride-28 rows -> consecutive
//      rows' b128 quad-starts overlap 3/4 within each 8-lane LDS phase.
//      Fix: LROW=32 + column XOR ((row&1)<<4). Adjacent rows' 4-quad sets
//      are exact complements (XOR-16 is the only delta disjoint from the
//      window's internal XOR-diffs {4,8,12,20,24,28}) -> 8 distinct quads
//      per phase -> conflict-free reads.
//  (b) ~2600 cyc/stage latency stall: VGPR=68 shows compiler did zero
//      LDS-read pipelining (read 3 -> lgkmcnt(0) -> 36 FMA, serial per ch).
//      Fix: explicit next-channel window prefetch into regs (+12 VGPR).
// Wave w owns dy = w-4; 16x16 tile, RX=4, acc[9][4]=36 regs.

#define Bn 4
#define Cn 256
#define Hn 96
#define Wn 160
#define HWn (Hn * Wn)
#define NP 81
#define TY 16
#define TX 16
#define CCH 8                 // channels per stage
#define NSTAGE (Cn / CCH)     // 32
#define WROWS (TY + 8)        // 24
#define SEGS 6                // float4 segments per 24-float data row
#define LROW 32               // padded+swizzled LDS row stride (floats)
#define F1C (WROWS * LROW)    // 768 floats per staged channel
#define BUF (CCH * F1C)       // 6144 floats per LDS buffer
#define NT 576                // 9 waves
#define F1STG (CCH * HWn / 4) // float4 stride between stages in f1

__global__ __launch_bounds__(NT, 3) void corr_kernel(const float* __restrict__ f0,
                                                     const float* __restrict__ f1,
                                                     float* __restrict__ out) {
    __shared__ __align__(16) float lds[2 * BUF];  // 49152 B double buffer

    const int tid  = threadIdx.x;
    const int wave = tid >> 6;      // 0..8 (dy = wave-4)
    const int lane = tid & 63;
    const int r    = lane >> 2;     // 0..15 tile row
    const int g    = lane & 3;      // 0..3  col group of 4 px

    // XCD-spatial swizzle: 240 blocks = 8 XCDs x 30 tiles (half-batch each).
    const int blk = blockIdx.x;
    const int xcd = blk & 7;
    const int it  = blk >> 3;           // 0..29
    const int b   = xcd >> 1;
    const int ty  = (xcd & 1) * 3 + it / 10;
    const int tx  = it % 10;
    const int y0  = ty * TY;
    const int x0  = tx * TX;

    // ---- staging map: 2 float4/thread/stage; copy 2 = same spot, channel +4
    const int scc  = tid / (WROWS * SEGS);        // 0..3
    const int srm  = tid - scc * (WROWS * SEGS);
    const int srr  = srm / SEGS;                  // 0..23 window row
    const int sseg = srm - srr * SEGS;            // 0..5
    const int sgy  = y0 - 4 + srr;
    const int sgx  = x0 - 4 + sseg * 4;           // mult of 4 -> seg all-in/out of [0,W)
    const bool sval = (sgy >= 0) && (sgy < Hn) && (sgx >= 0) && (sgx < Wn);
    const int swz   = (sseg * 4) ^ ((srr & 1) << 4);              // XOR-16 row-parity swizzle
    const int slidx = (scc * F1C + srr * LROW + swz) >> 2;        // float4 idx
    const int sgidx = sval ? ((((b * Cn + scc) * Hn + sgy) * Wn + sgx) >> 2) : 0;

    const float4* __restrict__ f1v = (const float4*)f1;
    float4* lv = (float4*)lds;

    // ---- read offsets (constant per lane; swizzle folded in, zero loop cost)
    const int q  = r + wave;                      // 0..23 window row
    const int xr = (q & 1) << 4;
    const int o0 = q * LROW + ((g * 4) ^ xr);
    const int o1 = q * LROW + ((g * 4 + 4) ^ xr);
    const int o2 = q * LROW + ((g * 4 + 8) ^ xr);

    // ---- prologue: prefetch stage 0
    float4 p1a = make_float4(0.f, 0.f, 0.f, 0.f), p1b = p1a;
    if (sval) { p1a = f1v[sgidx]; p1b = f1v[sgidx + HWn]; }   // ch scc, scc+4

    const float* f0s = f0 + ((b * Cn) * Hn + y0 + r) * Wn + x0 + g * 4;
    float4 p0[CCH];
#pragma unroll
    for (int cc = 0; cc < CCH; ++cc) p0[cc] = *(const float4*)(f0s + cc * HWn);

    float acc[9][4];
#pragma unroll
    for (int i = 0; i < 9; ++i)
#pragma unroll
        for (int j = 0; j < 4; ++j) acc[i][j] = 0.f;

    for (int s = 0; s < NSTAGE; ++s) {
        // publish stage s's f1 to buffer (s&1); safe vs compute s-2 (same
        // parity) via barrier at s-1; compute s reads after this barrier.
        float4* buf = lv + (s & 1) * (BUF / 4);
        buf[slidx]       = p1a;
        buf[slidx + F1C] = p1b;       // channel +4 -> +4*F1C floats = +F1C float4
        __syncthreads();              // single barrier per stage

        // depth-1 prefetch for stage s+1: in flight across the whole compute
        const int ns = (s + 1 < NSTAGE) ? s + 1 : NSTAGE - 1;
        float4 n1a = make_float4(0.f, 0.f, 0.f, 0.f), n1b = n1a;
        if (sval) { n1a = f1v[sgidx + ns * F1STG]; n1b = f1v[sgidx + ns * F1STG + HWn]; }
        float4 n0[CCH];
#pragma unroll
        for (int cc = 0; cc < CCH; ++cc)
            n0[cc] = *(const float4*)(f0s + (ns * CCH + cc) * HWn);

        // compute stage s: channel-pipelined window reads (hide ds_read latency)
        const float* bufF = &lds[(s & 1) * BUF];
        float4 a0 = *(const float4*)(bufF + o0);
        float4 a1 = *(const float4*)(bufF + o1);
        float4 a2 = *(const float4*)(bufF + o2);
#pragma unroll
        for (int cc = 0; cc < CCH; ++cc) {
            float4 b0, b1, b2;
            if (cc + 1 < CCH) {
                const float* nw = bufF + (cc + 1) * F1C;
                b0 = *(const float4*)(nw + o0);
                b1 = *(const float4*)(nw + o1);
                b2 = *(const float4*)(nw + o2);
            }
            float av[4]  = {p0[cc].x, p0[cc].y, p0[cc].z, p0[cc].w};
            float wv[12] = {a0.x, a0.y, a0.z, a0.w, a1.x, a1.y, a1.z, a1.w,
                            a2.x, a2.y, a2.z, a2.w};
#pragma unroll
            for (int dx = 0; dx < 9; ++dx)
#pragma unroll
                for (int rx = 0; rx < 4; ++rx)
                    acc[dx][rx] = fmaf(av[rx], wv[rx + dx], acc[dx][rx]);
            if (cc + 1 < CCH) { a0 = b0; a1 = b1; a2 = b2; }
        }

        p1a = n1a; p1b = n1b;
#pragma unroll
        for (int cc = 0; cc < CCH; ++cc) p0[cc] = n0[cc];
    }

    // ---- epilogue: exclusive ownership -> plain coalesced float4 stores
    const int orow = ((b * NP + wave * 9) * Hn + y0 + r) * Wn + x0 + g * 4;
#pragma unroll
    for (int dx = 0; dx < 9; ++dx)
        *(float4*)(out + orow + dx * HWn) =
            make_float4(acc[dx][0], acc[dx][1], acc[dx][2], acc[dx][3]);
}

extern "C" void kernel_launch(void* const* d_in, const int* in_sizes, int n_in,
                              void* d_out, int out_size, void* d_ws, size_t ws_size,
                              hipStream_t stream) {
    const float* f0 = (const float*)d_in[0];
    const float* f1 = (const float*)d_in[1];
    float* out = (float*)d_out;
    corr_kernel<<<dim3(240), NT, 0, stream>>>(f0, f1, out);
}